// Round 7
// baseline (848.203 us; speedup 1.0000x reference)
//
#include <hip/hip_runtime.h>
#include <hip/hip_fp16.h>

#define NN 50000
#define LL 4
#define DD 128
#define KDIM 16
#define EE 800000
#define MM (NN * LL)
#define DECAYF 0.7f
#define EPSF 1e-5f
#define SCAN_CHUNK 512
#define SCAN_NBLK ((NN + SCAN_CHUNK - 1) / SCAN_CHUNK)   // 98

typedef __attribute__((ext_vector_type(8))) short s16x8;   // 8 bf16 (4 VGPRs) MFMA frag
typedef __attribute__((ext_vector_type(4))) float fx4;     // MFMA accumulator

// within-wave LDS ordering: writes complete before subsequent reads (no cross-wave rendezvous).
// sched_barrier(0) both sides per guide rule #18 (hipcc can hoist reg-only ops past inline-asm waitcnt).
#define LDSFENCE() do { \
    __builtin_amdgcn_sched_barrier(0); \
    asm volatile("s_waitcnt lgkmcnt(0)" ::: "memory"); \
    __builtin_amdgcn_sched_barrier(0); \
} while (0)

// ---------- bf16 helpers (RNE) ----------
__device__ __forceinline__ short f2bf(float x) {
    unsigned u = __float_as_uint(x);
    u += 0x7fffu + ((u >> 16) & 1u);
    return (short)(u >> 16);
}
__device__ __forceinline__ float bf2f(short h) {
    return __uint_as_float(((unsigned)(unsigned short)h) << 16);
}
// fast silu: y * rcp(1+exp(-y)); error ~1e-7
__device__ __forceinline__ float silu(float y) {
    return y * __builtin_amdgcn_rcpf(1.f + __expf(-y));
}

// ---------- CSR build ----------
__global__ void k_zero(int* p, int n) {
    int i = blockIdx.x * 256 + threadIdx.x;
    if (i < n) p[i] = 0;
}
__global__ void k_hist(const int* __restrict__ rows, int* __restrict__ counts) {
    int e = blockIdx.x * 256 + threadIdx.x;
    if (e < EE) atomicAdd(&counts[rows[e]], 1);
}
__global__ void k_scan1(const int* __restrict__ counts, int* __restrict__ offs, int* __restrict__ csum) {
    __shared__ int s[SCAN_CHUNK];
    int i = blockIdx.x * SCAN_CHUNK + threadIdx.x;
    int v = (i < NN) ? counts[i] : 0;
    s[threadIdx.x] = v;
    __syncthreads();
    for (int off = 1; off < SCAN_CHUNK; off <<= 1) {
        int t = (threadIdx.x >= off) ? s[threadIdx.x - off] : 0;
        __syncthreads();
        s[threadIdx.x] += t;
        __syncthreads();
    }
    if (i < NN) offs[i] = s[threadIdx.x] - v;
    if (threadIdx.x == SCAN_CHUNK - 1) csum[blockIdx.x] = s[SCAN_CHUNK - 1];
}
__global__ void k_scan2(int* __restrict__ csum) {
    __shared__ int s[128];
    int v = (threadIdx.x < SCAN_NBLK) ? csum[threadIdx.x] : 0;
    s[threadIdx.x] = v;
    __syncthreads();
    for (int off = 1; off < 128; off <<= 1) {
        int t = (threadIdx.x >= off) ? s[threadIdx.x - off] : 0;
        __syncthreads();
        s[threadIdx.x] += t;
        __syncthreads();
    }
    if (threadIdx.x < SCAN_NBLK) csum[threadIdx.x] = s[threadIdx.x] - v;
}
__global__ void k_scan3(int* __restrict__ offs, const int* __restrict__ csum, int* __restrict__ cursor) {
    int i = blockIdx.x * SCAN_CHUNK + threadIdx.x;
    if (i < NN) {
        int v = offs[i] + csum[blockIdx.x];
        offs[i] = v;
        cursor[i] = v;
    } else if (i == NN) {
        offs[NN] = EE;
    }
}
// pack: (col, f32 val) — f32 vals REQUIRED: retentive-weight path is sign-sensitive
// (LN cancels |w|); fp16 vals flip signs of near-zero weights (round-3 failure).
__global__ void k_fill(const int* __restrict__ rows, const int* __restrict__ cols,
                       const float* __restrict__ vals,
                       int* __restrict__ cursor, int2* __restrict__ cpack) {
    int e = blockIdx.x * 256 + threadIdx.x;
    if (e < EE) {
        int r = rows[e];
        int pos = atomicAdd(&cursor[r], 1);
        cpack[pos] = make_int2(cols[e], __float_as_int(vals[e]));
    }
}

// ---------- x f32 -> fp16 ----------
__global__ __launch_bounds__(256) void k_xhalf(const float* __restrict__ x, __half* __restrict__ xh) {
    size_t i = (size_t)blockIdx.x * 256 + threadIdx.x;   // over M*D/4 = 6.4M
    float4 v = *reinterpret_cast<const float4*>(x + i * 4);
    __half2 h0 = __floats2half2_rn(v.x, v.y);
    __half2 h1 = __floats2half2_rn(v.z, v.w);
    __half2* d = reinterpret_cast<__half2*>(xh + i * 4);
    d[0] = h0;
    d[1] = h1;
}

// ---------- SAGE aggregation (fp16 x gather, f32 vals/accum) -> agg f32 ----------
__global__ __launch_bounds__(128) void k_agg_h(const int* __restrict__ offs,
                                               const int2* __restrict__ cpack,
                                               const __half* __restrict__ xh,
                                               float* __restrict__ agg) {
    int n = blockIdx.x;
    int hf = threadIdx.x >> 6;
    int lane = threadIdx.x & 63;
    int s = offs[n], e = offs[n + 1];
    const __half* b0 = xh + (size_t)(2 * hf) * NN * DD + lane * 2;
    const __half* b1 = xh + (size_t)(2 * hf + 1) * NN * DD + lane * 2;
    float a00 = 0.f, a01 = 0.f, a10 = 0.f, a11 = 0.f;
    #pragma unroll 2
    for (int p = s; p < e; p++) {
        int2 cw = cpack[p];
        int c = cw.x;
        float wv = __int_as_float(cw.y);
        float2 f0 = __half22float2(*reinterpret_cast<const __half2*>(b0 + (size_t)c * DD));
        float2 f1 = __half22float2(*reinterpret_cast<const __half2*>(b1 + (size_t)c * DD));
        a00 += wv * f0.x; a01 += wv * f0.y;
        a10 += wv * f1.x; a11 += wv * f1.y;
    }
    *reinterpret_cast<float2*>(agg + ((size_t)(2 * hf) * NN + n) * DD + lane * 2)     = make_float2(a00, a01);
    *reinterpret_cast<float2*>(agg + ((size_t)(2 * hf + 1) * NN + n) * DD + lane * 2) = make_float2(a10, a11);
}

// ---------- fallback f32 gather (small workspace) ----------
__global__ __launch_bounds__(128) void k_agg_f(const int* __restrict__ offs,
                                               const int2* __restrict__ cpack,
                                               const float* __restrict__ x,
                                               float* __restrict__ agg) {
    int n = blockIdx.x;
    int tid = threadIdx.x;    // = d
    int s = offs[n], e = offs[n + 1];
    float a0 = 0.f, a1 = 0.f, a2 = 0.f, a3 = 0.f;
    for (int p = s; p < e; p++) {
        int2 cw = cpack[p];
        int c = cw.x;
        float w = __int_as_float(cw.y);
        a0 += w * x[((size_t)(0 * NN + c)) * DD + tid];
        a1 += w * x[((size_t)(1 * NN + c)) * DD + tid];
        a2 += w * x[((size_t)(2 * NN + c)) * DD + tid];
        a3 += w * x[((size_t)(3 * NN + c)) * DD + tid];
    }
    agg[((size_t)(0 * NN + n)) * DD + tid] = a0;
    agg[((size_t)(1 * NN + n)) * DD + tid] = a1;
    agg[((size_t)(2 * NN + n)) * DD + tid] = a2;
    agg[((size_t)(3 * NN + n)) * DD + tid] = a3;
}

// ---------- weight prep: transpose + bf16 hi/lo split ----------
// out layout (shorts): sWh[16384] sWl | aWh aWl | vWh vWl | l1h[32768] l1l | l2h l2l | kqh[4096] kql
__global__ void k_wprep(const float* __restrict__ sW, const float* __restrict__ aW,
                        const float* __restrict__ vW, const float* __restrict__ w1,
                        const float* __restrict__ w2,
                        const float* __restrict__ wk, const float* __restrict__ wq,
                        short* __restrict__ out) {
    int b = blockIdx.x;   // 400 blocks x 256 threads
    if (b < 384) {
        const float* src; short* h; short* l; int K; int base;
        if (b < 64)       { src = sW; h = out;          l = out + 16384;  K = 128; base = b; }
        else if (b < 128) { src = aW; h = out + 32768;  l = out + 49152;  K = 128; base = b - 64; }
        else if (b < 192) { src = vW; h = out + 65536;  l = out + 81920;  K = 128; base = b - 128; }
        else if (b < 320) { src = w1; h = out + 98304;  l = out + 131072; K = 256; base = b - 192; }
        else              { src = w2; h = out + 163840; l = out + 180224; K = 128; base = b - 320; }
        int idx = base * 256 + threadIdx.x;   // over K*128, row-major [K][128]
        int k = idx >> 7, n = idx & 127;
        float v = src[idx];
        short hh = f2bf(v);
        h[n * K + k] = hh;                    // transposed: [n][K]
        l[n * K + k] = f2bf(v - bf2f(hh));
    } else {
        // kq: cols 0..15 = Wk^T, 16..31 = Wq^T, layout [32][128]
        int idx = (b - 384) * 256 + threadIdx.x;   // < 4096
        int j = idx >> 7, k = idx & 127;
        float v = (j < 16) ? wk[k * KDIM + j] : wq[k * KDIM + (j - 16)];
        short hh = f2bf(v);
        out[196608 + j * 128 + k] = hh;
        out[200704 + j * 128 + k] = f2bf(v - bf2f(hh));
    }
}

// ---------- wave-local stage: 16 rows x 128 f32 -> bf16 (hi, or hi+lo), row stride 136 ----------
__device__ __forceinline__ void wstage16h(const float* __restrict__ src, int rbase,
                                          short* __restrict__ h, int lane) {
    int row = lane >> 2, ko = (lane & 3) * 32;
    const float* gp = src + (size_t)(rbase + row) * DD + ko;
    short* dh = h + row * 136 + ko;
    #pragma unroll
    for (int j = 0; j < 4; j++) {
        float4 a = *reinterpret_cast<const float4*>(gp + j * 8);
        float4 b = *reinterpret_cast<const float4*>(gp + j * 8 + 4);
        s16x8 hv;
        hv[0] = f2bf(a.x); hv[1] = f2bf(a.y); hv[2] = f2bf(a.z); hv[3] = f2bf(a.w);
        hv[4] = f2bf(b.x); hv[5] = f2bf(b.y); hv[6] = f2bf(b.z); hv[7] = f2bf(b.w);
        *(s16x8*)(dh + j * 8) = hv;
    }
}
__device__ __forceinline__ void wstage16(const float* __restrict__ src, int rbase,
                                         short* __restrict__ h, short* __restrict__ l, int lane) {
    int row = lane >> 2, ko = (lane & 3) * 32;
    const float* gp = src + (size_t)(rbase + row) * DD + ko;
    short* dh = h + row * 136 + ko;
    short* dl = l + row * 136 + ko;
    #pragma unroll
    for (int j = 0; j < 4; j++) {
        float4 a = *reinterpret_cast<const float4*>(gp + j * 8);
        float4 b = *reinterpret_cast<const float4*>(gp + j * 8 + 4);
        float v[8] = {a.x, a.y, a.z, a.w, b.x, b.y, b.z, b.w};
        s16x8 hv, lv;
        #pragma unroll
        for (int e = 0; e < 8; e++) {
            short hh = f2bf(v[e]);
            hv[e] = hh;
            lv[e] = f2bf(v[e] - bf2f(hh));
        }
        *(s16x8*)(dh + j * 8) = hv;
        *(s16x8*)(dl + j * 8) = lv;
    }
}

// ---------- wave-local 16x128 GEMM pass, K=128, plain bf16 MFMA ----------
// A bf16 in wave-private LDS [16][136]; B = W^T hi-plane [128+][wlen] at koff.
// A-frag row = l16, k = ks*32+kg*8; C: row = kg*4+r, col = nt*16+l16 [m89].
__device__ __forceinline__ void mfma16(const short* __restrict__ a16,
                                       const short* __restrict__ Wh,
                                       int wlen, int koff, int l16, int kg,
                                       fx4 acc[8]) {
    #pragma unroll
    for (int ks = 0; ks < 4; ks++) {
        s16x8 ah = *(const s16x8*)(a16 + l16 * 136 + ks * 32 + kg * 8);
        #pragma unroll
        for (int nt = 0; nt < 8; nt++) {
            s16x8 bh = *(const s16x8*)(Wh + (nt * 16 + l16) * wlen + koff + ks * 32 + kg * 8);
            acc[nt] = __builtin_amdgcn_mfma_f32_16x16x32_bf16(ah, bh, acc[nt], 0, 0, 0);
        }
    }
}

// ---------- sage GEMMs + kq piggyback, wave-local (zero barriers) ----------
// io holds agg on entry; each wave owns 16 rows end-to-end. LN in registers.
__global__ __launch_bounds__(256, 4) void k_sage2(
    const float* __restrict__ x,
    const short* __restrict__ aWh,
    const short* __restrict__ sWh,
    const short* __restrict__ kqh, const short* __restrict__ kql,
    const float* __restrict__ bias, const float* __restrict__ g, const float* __restrict__ bb,
    float* __restrict__ wt_total, float* __restrict__ iw0,
    float* __restrict__ io) {
    __shared__ __align__(16) short stg[2][64 * 136];   // 34816 B, wave-partitioned
    const int tid = threadIdx.x;
    const int w = tid >> 6, lane = tid & 63;
    const int l16 = lane & 15, kg = lane >> 4;
    const int rbase = blockIdx.x * 64 + w * 16;
    short* ph = &stg[0][w * (16 * 136)];
    short* pl = &stg[1][w * (16 * 136)];

    fx4 acc[8];
    #pragma unroll
    for (int nt = 0; nt < 8; nt++) acc[nt] = (fx4){0.f, 0.f, 0.f, 0.f};

    // ---- agg (io) @ aggW ----
    wstage16h(io, rbase, ph, lane);
    LDSFENCE();
    mfma16(ph, aWh, 128, 0, l16, kg, acc);
    LDSFENCE();   // reads retired before overwrite

    // ---- x @ sageW + kq (hi/lo 3-term, sign-critical wt) ----
    wstage16(x, rbase, ph, pl, lane);
    LDSFENCE();
    mfma16(ph, sWh, 128, 0, l16, kg, acc);

    fx4 acck0 = (fx4){0.f, 0.f, 0.f, 0.f};
    fx4 acck1 = (fx4){0.f, 0.f, 0.f, 0.f};
    #pragma unroll
    for (int ks = 0; ks < 4; ks++) {
        int ao = l16 * 136 + ks * 32 + kg * 8;
        s16x8 ah = *(const s16x8*)(ph + ao);
        s16x8 al = *(const s16x8*)(pl + ao);
        int bo0 = l16 * 128 + ks * 32 + kg * 8;
        s16x8 bh0 = *(const s16x8*)(kqh + bo0);
        s16x8 bl0 = *(const s16x8*)(kql + bo0);
        acck0 = __builtin_amdgcn_mfma_f32_16x16x32_bf16(ah, bh0, acck0, 0, 0, 0);
        acck0 = __builtin_amdgcn_mfma_f32_16x16x32_bf16(ah, bl0, acck0, 0, 0, 0);
        acck0 = __builtin_amdgcn_mfma_f32_16x16x32_bf16(al, bh0, acck0, 0, 0, 0);
        int bo1 = (16 + l16) * 128 + ks * 32 + kg * 8;
        s16x8 bh1 = *(const s16x8*)(kqh + bo1);
        s16x8 bl1 = *(const s16x8*)(kql + bo1);
        acck1 = __builtin_amdgcn_mfma_f32_16x16x32_bf16(ah, bh1, acck1, 0, 0, 0);
        acck1 = __builtin_amdgcn_mfma_f32_16x16x32_bf16(ah, bl1, acck1, 0, 0, 0);
        acck1 = __builtin_amdgcn_mfma_f32_16x16x32_bf16(al, bh1, acck1, 0, 0, 0);
    }
    #pragma unroll
    for (int r = 0; r < 4; r++) {
        float pr = acck0[r] * acck1[r];
        pr += __shfl_xor(pr, 1, 64);
        pr += __shfl_xor(pr, 2, 64);
        pr += __shfl_xor(pr, 4, 64);
        pr += __shfl_xor(pr, 8, 64);
        if (l16 == 0) {
            int m = rbase + kg * 4 + r;
            int l = m / NN, n = m - l * NN;
            float sv = pr * (1.f / 16.f);
            wt_total[n * LL + l] = sv;
            iw0[n * LL + l] = sv;
        }
    }

    // ---- epilogue: silu(acc + bias), LN in registers, write io ----
    float br[8], gr[8], b2r[8];
    #pragma unroll
    for (int nt = 0; nt < 8; nt++) {
        int col = nt * 16 + l16;
        br[nt] = bias[col]; gr[nt] = g[col]; b2r[nt] = bb[col];
    }
    #pragma unroll
    for (int nt = 0; nt < 8; nt++)
        #pragma unroll
        for (int r = 0; r < 4; r++)
            acc[nt][r] = silu(acc[nt][r] + br[nt]);
    #pragma unroll
    for (int r = 0; r < 4; r++) {
        float s = 0.f, q = 0.f;
        #pragma unroll
        for (int nt = 0; nt < 8; nt++) { float v = acc[nt][r]; s += v; q += v * v; }
        s += __shfl_xor(s, 1, 64); q += __shfl_xor(q, 1, 64);
        s += __shfl_xor(s, 2, 64); q += __shfl_xor(q, 2, 64);
        s += __shfl_xor(s, 4, 64); q += __shfl_xor(q, 4, 64);
        s += __shfl_xor(s, 8, 64); q += __shfl_xor(q, 8, 64);
        float mu = s * (1.f / 128.f);
        float var = fmaxf(q * (1.f / 128.f) - mu * mu, 0.f);
        float rstd = rsqrtf(var + EPSF);
        size_t m = (size_t)rbase + kg * 4 + r;
        #pragma unroll
        for (int nt = 0; nt < 8; nt++)
            io[m * DD + nt * 16 + l16] = (acc[nt][r] - mu) * rstd * gr[nt] + b2r[nt];
    }
}

// ---------- fused lin1 + lin2, wave-local (zero barriers), register LN ----------
__global__ __launch_bounds__(256, 4) void k_lin12(
    const float* __restrict__ x,
    const short* __restrict__ Wvh,
    const float* __restrict__ wtbuf,
    const float* __restrict__ att_g, const float* __restrict__ att_b,
    const short* __restrict__ W1h,                                   // [128][256] transposed
    const float* __restrict__ b1v,
    const float* __restrict__ ln1g, const float* __restrict__ ln1b,
    const short* __restrict__ W2h,                                   // [128][128] transposed
    const float* __restrict__ b2v,
    const float* __restrict__ ln2g, const float* __restrict__ ln2b,
    float* __restrict__ io) {                                        // sage in, out in-place
    __shared__ __align__(16) short xt[64 * 136];
    __shared__ __align__(16) short atl[64 * 136];
    const int tid = threadIdx.x;
    const int w = tid >> 6, lane = tid & 63;
    const int l16 = lane & 15, kg = lane >> 4;
    const int rbase = blockIdx.x * 64 + w * 16;
    short* xw = xt + w * (16 * 136);
    short* aw = atl + w * (16 * 136);

    // T14: issue sage-row loads now; consumed at restage after att phase.
    float4 pf[8];
    {
        int row = lane >> 2, ko = (lane & 3) * 32;
        const float* gp = io + (size_t)(rbase + row) * DD + ko;
        #pragma unroll
        for (int j = 0; j < 8; j++) pf[j] = *reinterpret_cast<const float4*>(gp + j * 4);
    }

    // ---- att: v = x @ Wv ----
    wstage16h(x, rbase, xw, lane);
    LDSFENCE();
    fx4 acc[8];
    #pragma unroll
    for (int nt = 0; nt < 8; nt++) acc[nt] = (fx4){0.f, 0.f, 0.f, 0.f};
    mfma16(xw, Wvh, 128, 0, l16, kg, acc);

    // v * ws (per row), att LN in registers -> aw (bf16)
    {
        float ws[4];
        #pragma unroll
        for (int r = 0; r < 4; r++) {
            int m = rbase + kg * 4 + r;
            int l = m / NN, n = m - l * NN;
            ws[r] = wtbuf[n * LL + l];
        }
        #pragma unroll
        for (int nt = 0; nt < 8; nt++)
            #pragma unroll
            for (int r = 0; r < 4; r++) acc[nt][r] *= ws[r];
        float gA[8], bA[8];
        #pragma unroll
        for (int nt = 0; nt < 8; nt++) {
            int col = nt * 16 + l16;
            gA[nt] = att_g[col]; bA[nt] = att_b[col];
        }
        #pragma unroll
        for (int r = 0; r < 4; r++) {
            float s = 0.f, q = 0.f;
            #pragma unroll
            for (int nt = 0; nt < 8; nt++) { float v = acc[nt][r]; s += v; q += v * v; }
            s += __shfl_xor(s, 1, 64); q += __shfl_xor(q, 1, 64);
            s += __shfl_xor(s, 2, 64); q += __shfl_xor(q, 2, 64);
            s += __shfl_xor(s, 4, 64); q += __shfl_xor(q, 4, 64);
            s += __shfl_xor(s, 8, 64); q += __shfl_xor(q, 8, 64);
            float mu = s * (1.f / 128.f);
            float var = fmaxf(q * (1.f / 128.f) - mu * mu, 0.f);
            float rstd = rsqrtf(var + EPSF);
            int row = kg * 4 + r;
            #pragma unroll
            for (int nt = 0; nt < 8; nt++)
                aw[row * 136 + nt * 16 + l16] = f2bf((acc[nt][r] - mu) * rstd * gA[nt] + bA[nt]);
        }
    }

    // restage sage tile from prefetched regs -> xw
    {
        int row = lane >> 2, ko = (lane & 3) * 32;
        short* dh = xw + row * 136 + ko;
        #pragma unroll
        for (int j = 0; j < 4; j++) {
            float4 a = pf[2 * j], b = pf[2 * j + 1];
            s16x8 hv;
            hv[0] = f2bf(a.x); hv[1] = f2bf(a.y); hv[2] = f2bf(a.z); hv[3] = f2bf(a.w);
            hv[4] = f2bf(b.x); hv[5] = f2bf(b.y); hv[6] = f2bf(b.z); hv[7] = f2bf(b.w);
            *(s16x8*)(dh + j * 8) = hv;
        }
    }
    LDSFENCE();

    // ---- h1 = sage(xw) @ W1[:,0:128] + att(aw) @ W1[:,128:256] ----
    #pragma unroll
    for (int nt = 0; nt < 8; nt++) acc[nt] = (fx4){0.f, 0.f, 0.f, 0.f};
    mfma16(xw, W1h, 256, 0, l16, kg, acc);
    mfma16(aw, W1h, 256, 128, l16, kg, acc);

    // silu(h1+b1), LN1 in registers -> aw (bf16)
    {
        float b1r[8], g1r[8], bb1[8];
        #pragma unroll
        for (int nt = 0; nt < 8; nt++) {
            int col = nt * 16 + l16;
            b1r[nt] = b1v[col]; g1r[nt] = ln1g[col]; bb1[nt] = ln1b[col];
        }
        #pragma unroll
        for (int nt = 0; nt < 8; nt++)
            #pragma unroll
            for (int r = 0; r < 4; r++) acc[nt][r] = silu(acc[nt][r] + b1r[nt]);
        #pragma unroll
        for (int r = 0; r < 4; r++) {
            float s = 0.f, q = 0.f;
            #pragma unroll
            for (int nt = 0; nt < 8; nt++) { float v = acc[nt][r]; s += v; q += v * v; }
            s += __shfl_xor(s, 1, 64); q += __shfl_xor(q, 1, 64);
            s += __shfl_xor(s, 2, 64); q += __shfl_xor(q, 2, 64);
            s += __shfl_xor(s, 4, 64); q += __shfl_xor(q, 4, 64);
            s += __shfl_xor(s, 8, 64); q += __shfl_xor(q, 8, 64);
            float mu = s * (1.f / 128.f);
            float var = fmaxf(q * (1.f / 128.f) - mu * mu, 0.f);
            float rstd = rsqrtf(var + EPSF);
            int row = kg * 4 + r;
            #pragma unroll
            for (int nt = 0; nt < 8; nt++)
                aw[row * 136 + nt * 16 + l16] = f2bf((acc[nt][r] - mu) * rstd * g1r[nt] + bb1[nt]);
        }
    }
    LDSFENCE();

    // ---- out = LN2(silu(h1ln @ W2 + b2 + x)) ----
    #pragma unroll
    for (int nt = 0; nt < 8; nt++) acc[nt] = (fx4){0.f, 0.f, 0.f, 0.f};
    mfma16(aw, W2h, 128, 0, l16, kg, acc);
    {
        float b2r[8], g2r[8], bb2[8];
        #pragma unroll
        for (int nt = 0; nt < 8; nt++) {
            int col = nt * 16 + l16;
            b2r[nt] = b2v[col]; g2r[nt] = ln2g[col]; bb2[nt] = ln2b[col];
        }
        #pragma unroll
        for (int nt = 0; nt < 8; nt++)
            #pragma unroll
            for (int r = 0; r < 4; r++) {
                size_t m = (size_t)rbase + kg * 4 + r;
                acc[nt][r] = silu(acc[nt][r] + b2r[nt] + x[m * DD + nt * 16 + l16]);
            }
        #pragma unroll
        for (int r = 0; r < 4; r++) {
            float s = 0.f, q = 0.f;
            #pragma unroll
            for (int nt = 0; nt < 8; nt++) { float v = acc[nt][r]; s += v; q += v * v; }
            s += __shfl_xor(s, 1, 64); q += __shfl_xor(q, 1, 64);
            s += __shfl_xor(s, 2, 64); q += __shfl_xor(q, 2, 64);
            s += __shfl_xor(s, 4, 64); q += __shfl_xor(q, 4, 64);
            s += __shfl_xor(s, 8, 64); q += __shfl_xor(q, 8, 64);
            float mu = s * (1.f / 128.f);
            float var = fmaxf(q * (1.f / 128.f) - mu * mu, 0.f);
            float rstd = rsqrtf(var + EPSF);
            size_t m = (size_t)rbase + kg * 4 + r;
            #pragma unroll
            for (int nt = 0; nt < 8; nt++)
                io[m * DD + nt * 16 + l16] = (acc[nt][r] - mu) * rstd * g2r[nt] + bb2[nt];
        }
    }
}

// ---------- retentive weight iteration (f32 vals — sign-critical) ----------
__global__ __launch_bounds__(256) void k_spmm_w(const int* __restrict__ offs,
                                                const int2* __restrict__ cpack,
                                                const float* __restrict__ win, float* __restrict__ wout,
                                                float* __restrict__ wtot) {
    int i = blockIdx.x * 256 + threadIdx.x;
    if (i >= NN * LL) return;
    int n = i >> 2, l = i & 3;
    int s = offs[n], e = offs[n + 1];
    float a = 0.f;
    for (int p = s; p < e; p++) {
        int2 cw = cpack[p];
        a += __int_as_float(cw.y) * win[(cw.x << 2) | l];
    }
    a *= DECAYF;
    wout[i] = a;
    wtot[i] += a;
}

extern "C" void kernel_launch(void* const* d_in, const int* in_sizes, int n_in,
                              void* d_out, int out_size, void* d_ws, size_t ws_size,
                              hipStream_t stream) {
    const float* x        = (const float*)d_in[0];
    const int*   ei       = (const int*)d_in[1];
    const float* evals    = (const float*)d_in[2];
    const float* sage_W   = (const float*)d_in[3];
    const float* sage_b   = (const float*)d_in[4];
    const float* sage_aggW= (const float*)d_in[5];
    const float* sage_ln_g= (const float*)d_in[6];
    const float* sage_ln_b= (const float*)d_in[7];
    const float* att_Wk   = (const float*)d_in[8];
    const float* att_Wq   = (const float*)d_in[9];
    const float* att_Wv   = (const float*)d_in[10];
    const float* att_ln_g = (const float*)d_in[11];
    const float* att_ln_b = (const float*)d_in[12];
    const float* lin1_W   = (const float*)d_in[13];
    const float* lin1_b   = (const float*)d_in[14];
    const float* lin2_W   = (const float*)d_in[15];
    const float* lin2_b   = (const float*)d_in[16];
    const float* ln1_g    = (const float*)d_in[17];
    const float* ln1_b    = (const float*)d_in[18];
    const float* ln2_g    = (const float*)d_in[19];
    const float* ln2_b    = (const float*)d_in[20];

    const int* rows = ei;
    const int* cols = ei + EE;

    // ---- workspace layout ----
    float* wt_total = (float*)d_ws;                       // [M]
    float* iw0      = wt_total + MM;
    float* iw1      = iw0 + MM;
    int*   counts   = (int*)(iw1 + MM);                   // N
    int*   offs     = counts + NN;                        // N+1
    int*   cursor   = offs + NN + 1;                      // N
    int*   csum     = cursor + NN;                        // 128
    uintptr_t pc    = (uintptr_t)(csum + 128);
    pc = (pc + 15) & ~(uintptr_t)15;
    int2*  cpack    = (int2*)pc;                          // E (col, f32 valbits)
    uintptr_t pw    = (uintptr_t)(cpack + EE);
    pw = (pw + 15) & ~(uintptr_t)15;
    short* wbf      = (short*)pw;                         // 204800 shorts
    uintptr_t ph    = (uintptr_t)(wbf + 204800);
    ph = (ph + 255) & ~(uintptr_t)255;
    __half* xh      = (__half*)ph;                        // M*D fp16 = 51.2 MB (optional)
    size_t need_h   = (ph - (uintptr_t)d_ws) + (size_t)MM * DD * sizeof(__half);
    bool use_half   = ws_size >= need_h;
    float* io       = (float*)d_out;                      // [M,D] f32: agg -> sage -> out

    // ---- weight transpose+split ----
    k_wprep<<<400, 256, 0, stream>>>(sage_W, sage_aggW, att_Wv, lin1_W, lin2_W,
                                     att_Wk, att_Wq, wbf);

    // ---- CSR build ----
    k_zero<<<(NN + 255) / 256, 256, 0, stream>>>(counts, NN);
    k_hist<<<(EE + 255) / 256, 256, 0, stream>>>(rows, counts);
    k_scan1<<<SCAN_NBLK, SCAN_CHUNK, 0, stream>>>(counts, offs, csum);
    k_scan2<<<1, 128, 0, stream>>>(csum);
    k_scan3<<<SCAN_NBLK, SCAN_CHUNK, 0, stream>>>(offs, csum, cursor);
    k_fill<<<(EE + 255) / 256, 256, 0, stream>>>(rows, cols, evals, cursor, cpack);

    // ---- SAGE aggregation -> io ----
    if (use_half) {
        k_xhalf<<<(MM * DD / 4 + 255) / 256, 256, 0, stream>>>(x, xh);
        k_agg_h<<<NN, 128, 0, stream>>>(offs, cpack, xh, io);
    } else {
        k_agg_f<<<NN, 128, 0, stream>>>(offs, cpack, x, io);
    }

    // ---- sage GEMMs + kq -> io in-place, wt_total/iw0 ----
    k_sage2<<<MM / 64, 256, 0, stream>>>(
        x,
        wbf + 32768,                   // aggW hi
        wbf,                           // sageW hi
        wbf + 196608, wbf + 200704,    // kq hi/lo
        sage_b, sage_ln_g, sage_ln_b,
        wt_total, iw0, io);

    // ---- retentive weight iterations ----
    k_spmm_w<<<(MM + 255) / 256, 256, 0, stream>>>(offs, cpack, iw0, iw1, wt_total);
    k_spmm_w<<<(MM + 255) / 256, 256, 0, stream>>>(offs, cpack, iw1, iw0, wt_total);

    // ---- fused lin1+lin2 -> io (= d_out) in-place ----
    k_lin12<<<MM / 64, 256, 0, stream>>>(
        x, wbf + 65536, wt_total, att_ln_g, att_ln_b,
        wbf + 98304, lin1_b, ln1_g, ln1_b,
        wbf + 163840, lin2_b, ln2_g, ln2_b,
        io);

    (void)in_sizes; (void)n_in; (void)out_size;
}